// Round 1
// baseline (156.502 us; speedup 1.0000x reference)
//
#include <hip/hip_runtime.h>

#define B_ 16
#define N_ 2048
#define M_ 2048
#define D_ 64

typedef short sv8 __attribute__((ext_vector_type(8)));
typedef short sv4 __attribute__((ext_vector_type(4)));
typedef float fv4 __attribute__((ext_vector_type(4)));

__device__ __forceinline__ short f2bf(float x) {
    union { float f; unsigned u; } a; a.f = x;
    unsigned r = a.u + 0x7FFFu + ((a.u >> 16) & 1u);
    return (short)(r >> 16);
}
__device__ __forceinline__ float bf2f(short s) {
    union { float f; unsigned u; } a;
    a.u = ((unsigned)(unsigned short)s) << 16;
    return a.f;
}

// P_lds logical [16][2048] bf16, XOR-swizzled on 16B chunks so that
// phase-2 A-fragment ds_read_b128 (fixed m-chunk, r varying across lanes)
// spreads across all 8 bank windows. All accesses are >=4-elem aligned and
// stay within one 8-element chunk.
__device__ __forceinline__ int pidx(int r, int m) {
    return (r << 11) + ((((m >> 3) ^ (r & 7))) << 3) + (m & 7);
}

__global__ void conv_bf16(const float* __restrict__ in, short* __restrict__ outb) {
    int i = (blockIdx.x * 256 + threadIdx.x) * 4;
    float4 f = *(const float4*)(in + i);
    sv4 o; o[0] = f2bf(f.x); o[1] = f2bf(f.y); o[2] = f2bf(f.z); o[3] = f2bf(f.w);
    *(sv4*)(outb + i) = o;
}

// v[b][m][d] fp32 -> vt[b][d][m] bf16, 64x64 tiles through LDS
__global__ void conv_vt(const float* __restrict__ v, short* __restrict__ vt) {
    __shared__ short tile[64][65];
    int t = threadIdx.x;
    int b = blockIdx.x >> 5;
    int mt = (blockIdx.x & 31) << 6;
    for (int i = 0; i < 4; ++i) {
        int idx = i * 256 + t;
        int m = idx >> 4;
        int dq = (idx & 15) << 2;
        float4 f = *(const float4*)(v + ((size_t)(b * M_ + mt + m) * D_ + dq));
        tile[m][dq + 0] = f2bf(f.x); tile[m][dq + 1] = f2bf(f.y);
        tile[m][dq + 2] = f2bf(f.z); tile[m][dq + 3] = f2bf(f.w);
    }
    __syncthreads();
    for (int j = 0; j < 2; ++j) {
        int idx = j * 256 + t;
        int d = idx >> 3;
        int mq = (idx & 7) << 3;
        sv4 o0, o1;
        #pragma unroll
        for (int c = 0; c < 4; ++c) o0[c] = tile[mq + c][d];
        #pragma unroll
        for (int c = 0; c < 4; ++c) o1[c] = tile[mq + 4 + c][d];
        short* dst = vt + ((size_t)(b * D_ + d) * M_ + mt + mq);
        *(sv4*)(dst) = o0;
        *(sv4*)(dst + 4) = o1;
    }
}

// One block = one (b, 16-row n-tile). 4 waves / 256 threads.
__global__ __launch_bounds__(256, 2) void attn_main(
    const short* __restrict__ Qb, const short* __restrict__ Kb,
    const short* __restrict__ Vt, float* __restrict__ outp,
    float* __restrict__ attnp)
{
    __shared__ short P[16 * 2048];     // 64 KiB bf16 P (unnormalized exp scores)
    __shared__ float l_sh[4][16];
    __shared__ float rinv_sh[16];

    const int tid = threadIdx.x;
    const int w = tid >> 6;
    const int lane = tid & 63;
    const int r = lane & 15;
    const int g = lane >> 4;

    const int b = blockIdx.x >> 7;           // 128 n-tiles per batch
    const int n0 = (blockIdx.x & 127) << 4;

    // Q as MFMA B-operand fragments (col = n-row = lane&15, k = d)
    const short* qbase = Qb + ((b * N_ + n0 + r) * D_ + g * 8);
    sv8 q0 = *(const sv8*)(qbase);
    sv8 q1 = *(const sv8*)(qbase + 32);

    float lpart = 0.f;

    // Phase 1: S^T = K * Q^T, exp, bf16 P into LDS, partial row sums.
    for (int m0 = w * 16; m0 < M_; m0 += 64) {
        const short* kbase = Kb + ((b * M_ + m0 + r) * D_ + g * 8);
        sv8 a0 = *(const sv8*)(kbase);
        sv8 a1 = *(const sv8*)(kbase + 32);
        fv4 acc = {0.f, 0.f, 0.f, 0.f};
        acc = __builtin_amdgcn_mfma_f32_16x16x32_bf16(a0, q0, acc, 0, 0, 0);
        acc = __builtin_amdgcn_mfma_f32_16x16x32_bf16(a1, q1, acc, 0, 0, 0);
        // lane holds S^T[m0+g*4+reg][n0+r]  (D: col=lane&15 -> n, row=g*4+reg -> m)
        float p0 = __expf(fminf(acc[0] * 0.125f, 80.f));
        float p1 = __expf(fminf(acc[1] * 0.125f, 80.f));
        float p2 = __expf(fminf(acc[2] * 0.125f, 80.f));
        float p3 = __expf(fminf(acc[3] * 0.125f, 80.f));
        lpart += (p0 + p1) + (p2 + p3);
        sv4 pw; pw[0] = f2bf(p0); pw[1] = f2bf(p1); pw[2] = f2bf(p2); pw[3] = f2bf(p3);
        *(sv4*)&P[pidx(r, m0 + g * 4)] = pw;
    }

    // reduce partial sums across the 4 lane-groups, then across waves
    lpart += __shfl_xor(lpart, 16, 64);
    lpart += __shfl_xor(lpart, 32, 64);
    if (g == 0) l_sh[w][r] = lpart;
    __syncthreads();
    if (tid < 16) {
        float s = l_sh[0][tid] + l_sh[1][tid] + l_sh[2][tid] + l_sh[3][tid];
        rinv_sh[tid] = 1.f / s;
    }
    __syncthreads();

    // Phase 2a: normalized attn -> global (coalesced float4)
    const int base_row = b * N_ + n0;
    for (int i = 0; i < 32; ++i) {
        int idx = i * 256 + tid;
        int rr = idx >> 9;                 // 512 float4 per row
        int mq = (idx & 511) << 2;
        sv4 pv = *(const sv4*)&P[pidx(rr, mq)];
        float ri = rinv_sh[rr];
        float4 o;
        o.x = bf2f(pv[0]) * ri; o.y = bf2f(pv[1]) * ri;
        o.z = bf2f(pv[2]) * ri; o.w = bf2f(pv[3]) * ri;
        *(float4*)(attnp + ((size_t)(base_row + rr) * M_ + mq)) = o;
    }

    // Phase 2b: out = (P @ V) * rinv.  Wave w owns d-slice [w*16, w*16+16).
    fv4 acc = {0.f, 0.f, 0.f, 0.f};
    const short* vbase = Vt + ((size_t)(b * D_ + w * 16 + r) * M_);
    for (int m0 = 0; m0 < M_; m0 += 32) {
        sv8 pa = *(const sv8*)&P[pidx(r, m0 + g * 8)];
        sv8 vb = *(const sv8*)(vbase + m0 + g * 8);
        acc = __builtin_amdgcn_mfma_f32_16x16x32_bf16(pa, vb, acc, 0, 0, 0);
    }
    #pragma unroll
    for (int reg = 0; reg < 4; ++reg) {
        int nr = g * 4 + reg;              // D: col=lane&15 -> d, row=g*4+reg -> n
        outp[(size_t)(base_row + nr) * D_ + w * 16 + r] = acc[reg] * rinv_sh[nr];
    }
}

extern "C" void kernel_launch(void* const* d_in, const int* in_sizes, int n_in,
                              void* d_out, int out_size, void* d_ws, size_t ws_size,
                              hipStream_t stream) {
    const float* q = (const float*)d_in[0];
    const float* k = (const float*)d_in[1];
    const float* v = (const float*)d_in[2];
    float* outp = (float*)d_out;
    float* attnp = outp + (size_t)B_ * N_ * D_;

    short* Qb = (short*)d_ws;                       // 4 MiB
    short* Kb = Qb + (size_t)B_ * N_ * D_;          // 4 MiB
    short* Vt = Kb + (size_t)B_ * M_ * D_;          // 4 MiB (transposed [b][d][m])

    conv_bf16<<<2048, 256, 0, stream>>>(q, Qb);
    conv_bf16<<<2048, 256, 0, stream>>>(k, Kb);
    conv_vt<<<512, 256, 0, stream>>>(v, Vt);
    attn_main<<<B_ * (N_ / 16), 256, 0, stream>>>(Qb, Kb, Vt, outp, attnp);
}